// Round 15
// baseline (286.946 us; speedup 1.0000x reference)
//
#include <hip/hip_runtime.h>
#include <math.h>

// ---------------------------------------------------------------------------
// SplineConv GNN, 3 layers, K=5, dim=2, mean aggr, root+bias, ReLU, FC+sigmoid.
//
// Round 15 = round 14 (best, 282.7us) + ONE isolated change: csr16 keeps the
// 2-channels/thread structure (8 threads/edge, the R14 win) but reverts the
// LDS geometry to R13's measured-conflict-free layout (rows o*12 dwords,
// k stride 192, staging byte-identical to R13: 6.5e5 conflict cycles vs
// R14's new c*20 geometry at 8.1e6 ~ 13us/dispatch). Thread handles channels
// c and c+8 -> reads rows c and c+8 (the +96 dword offset is 0 mod 32, same
// bank pattern, 2-way = free).
// ---------------------------------------------------------------------------

#define KS 5
#define BW 512          // bucket width (nodes); B <= 256 for N <= 131072
#define TILE 4096       // edges per bin block

typedef _Float16 h2f __attribute__((ext_vector_type(2)));

__device__ __forceinline__ h2f u2h(unsigned u) { return __builtin_bit_cast(h2f, u); }

#if __has_builtin(__builtin_amdgcn_fdot2)
__device__ __forceinline__ float fdot2(h2f a, h2f b, float c) {
    return __builtin_amdgcn_fdot2(a, b, c, false);
}
#else
__device__ __forceinline__ float fdot2(h2f a, h2f b, float c) {
    return c + (float)a[0] * (float)b[0] + (float)a[1] * (float)b[1];
}
#endif

__device__ __forceinline__ unsigned packh2(float lo, float hi) {
    return (unsigned)__builtin_bit_cast(ushort, (_Float16)lo) |
           ((unsigned)__builtin_bit_cast(ushort, (_Float16)hi) << 16);
}

// ---- A0: bucket histogram ---------------------------------------------------
__global__ void bucket_hist_kernel(const int* __restrict__ dst, int* __restrict__ bcnt,
                                   int E, int B) {
    __shared__ int lh[256];
    lh[threadIdx.x] = 0;
    __syncthreads();
    int stride = gridDim.x * blockDim.x;
    for (int e = blockIdx.x * blockDim.x + threadIdx.x; e < E; e += stride)
        atomicAdd(&lh[dst[e] >> 9], 1);
    __syncthreads();
    int c = lh[threadIdx.x];
    if ((int)threadIdx.x < B && c) atomicAdd(&bcnt[threadIdx.x], c);
}

// ---- A1: bucket scan (1 block) + cursor init --------------------------------
__global__ void bucket_scan_kernel(const int* __restrict__ bcnt, int* __restrict__ bbase,
                                   int* __restrict__ bcursor, int B, int E) {
    __shared__ int sh[256];
    int v = ((int)threadIdx.x < B) ? bcnt[threadIdx.x] : 0;
    sh[threadIdx.x] = v;
    __syncthreads();
    for (int off = 1; off < 256; off <<= 1) {
        int t = (threadIdx.x >= (unsigned)off) ? sh[threadIdx.x - off] : 0;
        __syncthreads();
        sh[threadIdx.x] += t;
        __syncthreads();
    }
    if ((int)threadIdx.x < B) {
        bbase[threadIdx.x] = sh[threadIdx.x] - v;   // exclusive
        bcursor[threadIdx.x] = 0;
    }
    if (threadIdx.x == 0) bbase[B] = E;
}

// ---- A2: tile-radix bin -----------------------------------------------------
// bin rec = { src | dloc_lo8<<17 | w00<<25 | dloc_hi1<<30 , f16(f0)|f16(f1)<<16 }
__global__ __launch_bounds__(256) void bin_kernel(
        const float* __restrict__ eattr, const int* __restrict__ src,
        const int* __restrict__ dst, const int* __restrict__ bbase,
        int* __restrict__ bcursor, uint2* __restrict__ bin, int E) {
    __shared__ int lh[256];
    __shared__ int labs[256];
    __shared__ int lcur[256];
    lh[threadIdx.x] = 0;
    lcur[threadIdx.x] = 0;
    __syncthreads();
    int t0 = blockIdx.x * TILE;
    #pragma unroll
    for (int it = 0; it < TILE / 256; ++it) {
        int e = t0 + it * 256 + threadIdx.x;
        if (e < E) atomicAdd(&lh[dst[e] >> 9], 1);
    }
    __syncthreads();
    {
        int c = lh[threadIdx.x];
        if (c) labs[threadIdx.x] = bbase[threadIdx.x] + atomicAdd(&bcursor[threadIdx.x], c);
    }
    __syncthreads();
    #pragma unroll
    for (int it = 0; it < TILE / 256; ++it) {
        int e = t0 + it * 256 + threadIdx.x;
        if (e < E) {
            float2 ea = reinterpret_cast<const float2*>(eattr)[e];
            float a0 = ea.x * (float)(KS - 1);
            float a1 = ea.y * (float)(KS - 1);
            float k0 = fminf(fmaxf(floorf(a0), 0.0f), (float)(KS - 2));
            float k1 = fminf(fmaxf(floorf(a1), 0.0f), (float)(KS - 2));
            float f0 = a0 - k0, f1 = a1 - k1;
            unsigned w00 = (unsigned)((int)k0 + KS * (int)k1);
            int d = dst[e];
            int b = d >> 9;
            unsigned dloc = (unsigned)(d & 511);
            unsigned w0 = (unsigned)src[e] | ((dloc & 255u) << 17) | (w00 << 25) |
                          ((dloc >> 8) << 30);
            int p = atomicAdd(&lcur[b], 1);
            bin[labs[b] + p] = make_uint2(w0, packh2(f0, f1));
        }
    }
}

// ---- A3: within-bucket scatter to CSR + offs emission ----------------------
__global__ __launch_bounds__(256) void bucket_scatter_kernel(
        const uint2* __restrict__ bin, const int* __restrict__ bbase,
        uint2* __restrict__ epack, int* __restrict__ offs, int N, int E) {
    __shared__ int lcnt[512];
    __shared__ int loff[512];
    __shared__ int lcur[512];
    __shared__ int ssc[256];
    int tid = threadIdx.x;
    int b = blockIdx.x;
    int base = bbase[b];
    int cntb = bbase[b + 1] - base;
    int nbase = b << 9;
    lcnt[tid] = 0; lcnt[tid + 256] = 0;
    lcur[tid] = 0; lcur[tid + 256] = 0;
    __syncthreads();
    for (int r = tid; r < cntb; r += 256) {
        unsigned w0 = bin[base + r].x;
        int dloc = (int)(((w0 >> 17) & 255u) | (((w0 >> 30) & 1u) << 8));
        atomicAdd(&lcnt[dloc], 1);
    }
    __syncthreads();
    int a0 = lcnt[2 * tid], a1 = lcnt[2 * tid + 1];
    ssc[tid] = a0 + a1;
    __syncthreads();
    for (int off = 1; off < 256; off <<= 1) {
        int t = (tid >= off) ? ssc[tid - off] : 0;
        __syncthreads();
        ssc[tid] += t;
        __syncthreads();
    }
    int ex = (tid > 0) ? ssc[tid - 1] : 0;
    loff[2 * tid] = ex;
    loff[2 * tid + 1] = ex + a0;
    __syncthreads();
    for (int i = tid; i < 512; i += 256) {
        int n = nbase + i;
        if (n < N) offs[n] = base + loff[i];
    }
    if (b == 0 && tid == 0) offs[N] = E;
    for (int r = tid; r < cntb; r += 256) {
        uint2 rec = bin[base + r];
        int dloc = (int)(((rec.x >> 17) & 255u) | (((rec.x >> 30) & 1u) << 8));
        int p = atomicAdd(&lcur[dloc], 1);
        epack[base + loff[dloc] + p] = make_uint2(rec.x & 0x3E01FFFFu, rec.y);
    }
}

__device__ __forceinline__ void decode8(uint2 pk, int& s, float b[4], int wi[4]) {
    s = (int)(pk.x & 0x1FFFFFFu);
    int w00 = (int)((pk.x >> 25) & 31u);
    wi[0] = w00; wi[1] = w00 + 1; wi[2] = w00 + KS; wi[3] = w00 + KS + 1;
    h2f f = u2h(pk.y);
    float f0 = (float)f[0], f1 = (float)f[1];
    float g0 = 1.0f - f0, g1 = 1.0f - f1;
    b[0] = g0 * g1; b[1] = f0 * g1; b[2] = g0 * f1; b[3] = f0 * f1;
}

// ---- fused layer 1: x[N,2] f32 -> h f16, CSR aggregation -------------------
__global__ __launch_bounds__(256, 8) void csr2_kernel(
        const float* __restrict__ x,
        const uint2* __restrict__ epack,
        const int* __restrict__ offs,
        const float* __restrict__ W,      // [25,2,16]
        const float* __restrict__ root,   // [2,16]
        const float* __restrict__ bias,   // [16]
        ushort* __restrict__ hout,        // [N,16] f16
        int N) {
    __shared__ float Wl[25 * 32];
    for (int idx = threadIdx.x; idx < 25 * 32; idx += blockDim.x) {
        int k = idx >> 5;
        int r = idx & 31;
        int i = r >> 4;
        int o = r & 15;
        Wl[k * 32 + o * 2 + i] = W[idx];
    }
    __syncthreads();

    int t = blockIdx.x * blockDim.x + threadIdx.x;
    if (t >= N * 16) return;
    int o = t & 15;
    int n = t >> 4;
    int row = offs[n], end = offs[n + 1];

    float acc = 0.0f;
    uint2 pk = epack[(row < end) ? row : 0];
    for (int j = row; j < end; ++j) {
        uint2 cur = pk;
        int jn = j + 1;
        pk = epack[(jn < end) ? jn : j];
        int s;
        float b[4];
        int wi[4];
        decode8(cur, s, b, wi);
        float2 xv = reinterpret_cast<const float2*>(x)[s];
        #pragma unroll
        for (int sp = 0; sp < 4; ++sp) {
            float2 w = *reinterpret_cast<const float2*>(&Wl[wi[sp] * 32 + o * 2]);
            acc += b[sp] * (xv.x * w.x + xv.y * w.y);
        }
    }
    float inv = 1.0f / fmaxf((float)(end - row), 1.0f);
    float2 xn = reinterpret_cast<const float2*>(x)[n];
    acc = acc * inv + xn.x * root[o] + xn.y * root[16 + o] + bias[o];
    hout[t] = __builtin_bit_cast(ushort, (_Float16)fmaxf(acc, 0.0f));
}

// ---- fused layers 2/3: 2 channels/thread, R13 LDS geometry -----------------
// LDS: identical to R13 (rows o*12 dwords, 8 dwords used, k stride 192,
// root at 4800; staging byte-identical -> measured 6.5e5 conflicts).
// Thread c (= t&7) handles channels c and c+8: reads rows c (s0 = c*12) and
// c+8 (s0+96; 96 == 0 mod 32, same free bank pattern).
// FUSE_FC=1: 8-lane shfl reduce with fcw, lane c==0 writes sigmoid out[n].
template <int FUSE_FC>
__global__ __launch_bounds__(256, 8) void csr16c_kernel(
        const ushort* __restrict__ hh,
        const uint2* __restrict__ epack,
        const int* __restrict__ offs,
        const float* __restrict__ W,      // [25,16,16] f32
        const float* __restrict__ root,   // [16,16] f32
        const float* __restrict__ bias,   // [16]
        ushort* __restrict__ hout,        // [N,16] f16 (FUSE_FC=0)
        const float* __restrict__ fcw,    // [16]       (FUSE_FC=1)
        const float* __restrict__ fcb,    // [1]        (FUSE_FC=1)
        float* __restrict__ out,          // [N]        (FUSE_FC=1)
        int N) {
    __shared__ unsigned Wl[25 * 192 + 192];
    for (int idx = threadIdx.x; idx < 25 * 128 + 128; idx += blockDim.x) {
        if (idx < 25 * 128) {
            int k = idx >> 7;
            int d = idx & 127;
            int o = d >> 3;
            int j = d & 7;
            int i0 = ((j >> 2) << 3) + ((j & 3) << 1);
            Wl[k * 192 + o * 12 + j] =
                packh2(W[k * 256 + i0 * 16 + o], W[k * 256 + (i0 + 1) * 16 + o]);
        } else {
            int d = idx - 25 * 128;
            int o = d >> 3;
            int j = d & 7;
            int i0 = ((j >> 2) << 3) + ((j & 3) << 1);
            Wl[4800 + o * 12 + j] = packh2(root[i0 * 16 + o], root[(i0 + 1) * 16 + o]);
        }
    }
    __syncthreads();

    int t = blockIdx.x * blockDim.x + threadIdx.x;
    if (t >= N * 8) return;
    int c = t & 7;
    int n = t >> 3;
    int row = offs[n], end = offs[n + 1];
    int s0 = c * 12;          // row for channel c
    int s1 = s0 + 96;         // row for channel c+8 (96 == 0 mod 32)

    float acc0 = 0.0f, acc1 = 0.0f;
    uint2 pk = epack[(row < end) ? row : 0];
    for (int j = row; j < end; ++j) {
        uint2 cur = pk;
        int jn = j + 1;
        pk = epack[(jn < end) ? jn : j];
        int s;
        float b[4];
        int wi[4];
        decode8(cur, s, b, wi);
        const uint4* hp = reinterpret_cast<const uint4*>(hh + (size_t)s * 16);
        uint4 ha = hp[0], hb = hp[1];
        #pragma unroll
        for (int sp = 0; sp < 4; ++sp) {
            int kb = wi[sp] * 192;
            uint4 wa = *reinterpret_cast<const uint4*>(&Wl[kb + s0]);
            uint4 wb = *reinterpret_cast<const uint4*>(&Wl[kb + s0 + 4]);
            uint4 wc = *reinterpret_cast<const uint4*>(&Wl[kb + s1]);
            uint4 wd = *reinterpret_cast<const uint4*>(&Wl[kb + s1 + 4]);
            float p0 = 0.0f, p1 = 0.0f;
            p0 = fdot2(u2h(ha.x), u2h(wa.x), p0);
            p0 = fdot2(u2h(ha.y), u2h(wa.y), p0);
            p0 = fdot2(u2h(ha.z), u2h(wa.z), p0);
            p0 = fdot2(u2h(ha.w), u2h(wa.w), p0);
            p0 = fdot2(u2h(hb.x), u2h(wb.x), p0);
            p0 = fdot2(u2h(hb.y), u2h(wb.y), p0);
            p0 = fdot2(u2h(hb.z), u2h(wb.z), p0);
            p0 = fdot2(u2h(hb.w), u2h(wb.w), p0);
            p1 = fdot2(u2h(ha.x), u2h(wc.x), p1);
            p1 = fdot2(u2h(ha.y), u2h(wc.y), p1);
            p1 = fdot2(u2h(ha.z), u2h(wc.z), p1);
            p1 = fdot2(u2h(ha.w), u2h(wc.w), p1);
            p1 = fdot2(u2h(hb.x), u2h(wd.x), p1);
            p1 = fdot2(u2h(hb.y), u2h(wd.y), p1);
            p1 = fdot2(u2h(hb.z), u2h(wd.z), p1);
            p1 = fdot2(u2h(hb.w), u2h(wd.w), p1);
            acc0 = fmaf(b[sp], p0, acc0);
            acc1 = fmaf(b[sp], p1, acc1);
        }
    }
    float inv = 1.0f / fmaxf((float)(end - row), 1.0f);
    acc0 *= inv;
    acc1 *= inv;
    {
        const uint4* hp = reinterpret_cast<const uint4*>(hh + (size_t)n * 16);
        uint4 ha = hp[0], hb = hp[1];
        uint4 ra = *reinterpret_cast<const uint4*>(&Wl[4800 + s0]);
        uint4 rb = *reinterpret_cast<const uint4*>(&Wl[4800 + s0 + 4]);
        uint4 rc = *reinterpret_cast<const uint4*>(&Wl[4800 + s1]);
        uint4 rd = *reinterpret_cast<const uint4*>(&Wl[4800 + s1 + 4]);
        float p0 = 0.0f, p1 = 0.0f;
        p0 = fdot2(u2h(ha.x), u2h(ra.x), p0);
        p0 = fdot2(u2h(ha.y), u2h(ra.y), p0);
        p0 = fdot2(u2h(ha.z), u2h(ra.z), p0);
        p0 = fdot2(u2h(ha.w), u2h(ra.w), p0);
        p0 = fdot2(u2h(hb.x), u2h(rb.x), p0);
        p0 = fdot2(u2h(hb.y), u2h(rb.y), p0);
        p0 = fdot2(u2h(hb.z), u2h(rb.z), p0);
        p0 = fdot2(u2h(hb.w), u2h(rb.w), p0);
        p1 = fdot2(u2h(ha.x), u2h(rc.x), p1);
        p1 = fdot2(u2h(ha.y), u2h(rc.y), p1);
        p1 = fdot2(u2h(ha.z), u2h(rc.z), p1);
        p1 = fdot2(u2h(ha.w), u2h(rc.w), p1);
        p1 = fdot2(u2h(hb.x), u2h(rd.x), p1);
        p1 = fdot2(u2h(hb.y), u2h(rd.y), p1);
        p1 = fdot2(u2h(hb.z), u2h(rd.z), p1);
        p1 = fdot2(u2h(hb.w), u2h(rd.w), p1);
        acc0 += p0 + bias[c];
        acc1 += p1 + bias[c + 8];
    }
    float h0 = fmaxf(acc0, 0.0f);
    float h1 = fmaxf(acc1, 0.0f);
    if (FUSE_FC == 0) {
        hout[(size_t)n * 16 + c] = __builtin_bit_cast(ushort, (_Float16)h0);
        hout[(size_t)n * 16 + c + 8] = __builtin_bit_cast(ushort, (_Float16)h1);
    } else {
        float partial = h0 * fcw[c] + h1 * fcw[c + 8];
        partial += __shfl_xor(partial, 1, 8);
        partial += __shfl_xor(partial, 2, 8);
        partial += __shfl_xor(partial, 4, 8);
        if (c == 0) out[n] = 1.0f / (1.0f + expf(-(partial + fcb[0])));
    }
}

// ---- final FC + sigmoid (fallback paths only) ------------------------------
__global__ void fc_kernel(const ushort* __restrict__ h,
                          const float* __restrict__ fcw,
                          const float* __restrict__ fcb,
                          float* __restrict__ out, int N) {
    int n = blockIdx.x * blockDim.x + threadIdx.x;
    if (n >= N) return;
    const uint4* hp = reinterpret_cast<const uint4*>(h + (size_t)n * 16);
    uint4 ha = hp[0], hb = hp[1];
    unsigned dw[8] = {ha.x, ha.y, ha.z, ha.w, hb.x, hb.y, hb.z, hb.w};
    float acc = fcb[0];
    #pragma unroll
    for (int j = 0; j < 8; ++j) {
        h2f p = u2h(dw[j]);
        acc += (float)p[0] * fcw[2 * j] + (float)p[1] * fcw[2 * j + 1];
    }
    out[n] = 1.0f / (1.0f + expf(-acc));
}

// ---------------------------------------------------------------------------
// Fallback path (ws too small or N too large): atomic kernels.
// ---------------------------------------------------------------------------
__global__ void deg_count_kernel(const int* __restrict__ dst, float* __restrict__ deg, int E) {
    int stride = gridDim.x * blockDim.x;
    for (int e = blockIdx.x * blockDim.x + threadIdx.x; e < E; e += stride)
        atomicAdd(&deg[dst[e]], 1.0f);
}
__global__ void deg_inv_kernel(float* __restrict__ deg, int N) {
    int i = blockIdx.x * blockDim.x + threadIdx.x;
    if (i < N) deg[i] = 1.0f / fmaxf(deg[i], 1.0f);
}
__device__ __forceinline__ void compute_basis(const float* eattr, const int* srcp, int e,
                                              int& s, float b[4], int wi[4]) {
    float2 ea = reinterpret_cast<const float2*>(eattr)[e];
    float a0 = ea.x * (float)(KS - 1);
    float a1 = ea.y * (float)(KS - 1);
    float k0 = fminf(fmaxf(floorf(a0), 0.0f), (float)(KS - 2));
    float k1 = fminf(fmaxf(floorf(a1), 0.0f), (float)(KS - 2));
    float f0 = a0 - k0, f1 = a1 - k1;
    int i0 = (int)k0, i1 = (int)k1;
    int w00 = i0 + KS * i1;
    wi[0] = w00; wi[1] = w00 + 1; wi[2] = w00 + KS; wi[3] = w00 + KS + 1;
    float g0 = 1.0f - f0, g1 = 1.0f - f1;
    b[0] = g0 * g1; b[1] = f0 * g1; b[2] = g0 * f1; b[3] = f0 * f1;
    s = srcp[e];
}
__global__ __launch_bounds__(256) void edge16h_fb(
        const ushort* __restrict__ hh, const int* __restrict__ dst,
        const float* __restrict__ eattr, const int* __restrict__ srcp,
        const float* __restrict__ W, float* __restrict__ agg, int E) {
    __shared__ unsigned Wl[25 * 192];
    for (int idx = threadIdx.x; idx < 25 * 128; idx += blockDim.x) {
        int k = idx >> 7;
        int d = idx & 127;
        int o = d >> 3;
        int j = d & 7;
        int i0 = ((j >> 2) << 3) + ((j & 3) << 1);
        Wl[k * 192 + o * 12 + j] =
            packh2(W[k * 256 + i0 * 16 + o], W[k * 256 + (i0 + 1) * 16 + o]);
    }
    __syncthreads();
    int gs = gridDim.x * blockDim.x;
    int total = E * 16;
    for (int t = blockIdx.x * blockDim.x + threadIdx.x; t < total; t += gs) {
        int e = t >> 4;
        int o = t & 15;
        int s;
        float b[4];
        int wi[4];
        compute_basis(eattr, srcp, e, s, b, wi);
        const uint4* hp = reinterpret_cast<const uint4*>(hh + (size_t)s * 16);
        uint4 ha = hp[0], hb = hp[1];
        float acc = 0.0f;
        #pragma unroll
        for (int sp = 0; sp < 4; ++sp) {
            int kb = wi[sp] * 192 + o * 12;
            uint4 wa = *reinterpret_cast<const uint4*>(&Wl[kb]);
            uint4 wb = *reinterpret_cast<const uint4*>(&Wl[kb + 4]);
            float p = 0.0f;
            p = fdot2(u2h(ha.x), u2h(wa.x), p);
            p = fdot2(u2h(ha.y), u2h(wa.y), p);
            p = fdot2(u2h(ha.z), u2h(wa.z), p);
            p = fdot2(u2h(ha.w), u2h(wa.w), p);
            p = fdot2(u2h(hb.x), u2h(wb.x), p);
            p = fdot2(u2h(hb.y), u2h(wb.y), p);
            p = fdot2(u2h(hb.z), u2h(wb.z), p);
            p = fdot2(u2h(hb.w), u2h(wb.w), p);
            acc = fmaf(b[sp], p, acc);
        }
        atomicAdd(&agg[(size_t)dst[e] * 16 + o], acc);
    }
}
__global__ __launch_bounds__(256) void edge2_fb(
        const float* __restrict__ x, const int* __restrict__ dst,
        const float* __restrict__ eattr, const int* __restrict__ srcp,
        const float* __restrict__ W, float* __restrict__ agg, int E) {
    __shared__ float Wl[25 * 32];
    for (int idx = threadIdx.x; idx < 25 * 32; idx += blockDim.x) {
        int k = idx >> 5;
        int r = idx & 31;
        int i = r >> 4;
        int o = r & 15;
        Wl[k * 32 + o * 2 + i] = W[idx];
    }
    __syncthreads();
    int gs = gridDim.x * blockDim.x;
    int total = E * 16;
    for (int t = blockIdx.x * blockDim.x + threadIdx.x; t < total; t += gs) {
        int e = t >> 4;
        int o = t & 15;
        int s;
        float b[4];
        int wi[4];
        compute_basis(eattr, srcp, e, s, b, wi);
        float2 xv = reinterpret_cast<const float2*>(x)[s];
        float acc = 0.0f;
        #pragma unroll
        for (int sp = 0; sp < 4; ++sp) {
            float2 w = *reinterpret_cast<const float2*>(&Wl[wi[sp] * 32 + o * 2]);
            acc += b[sp] * (xv.x * w.x + xv.y * w.y);
        }
        atomicAdd(&agg[(size_t)dst[e] * 16 + o], acc);
    }
}
__global__ void finalize2h_fb(const float* __restrict__ x, const float* __restrict__ root,
                              const float* __restrict__ bias, const float* __restrict__ invdeg,
                              const float* __restrict__ agg, ushort* __restrict__ hout, int N) {
    int t = blockIdx.x * blockDim.x + threadIdx.x;
    if (t >= N * 16) return;
    int o = t & 15;
    int n = t >> 4;
    float2 xv = reinterpret_cast<const float2*>(x)[n];
    float acc = agg[t] * invdeg[n] + xv.x * root[o] + xv.y * root[16 + o] + bias[o];
    hout[t] = __builtin_bit_cast(ushort, (_Float16)fmaxf(acc, 0.0f));
}
__global__ void finalize16h_fb(const ushort* __restrict__ hin, const float* __restrict__ root,
                               const float* __restrict__ bias, const float* __restrict__ invdeg,
                               const float* __restrict__ agg, ushort* __restrict__ hout, int N) {
    int t = blockIdx.x * blockDim.x + threadIdx.x;
    if (t >= N * 16) return;
    int o = t & 15;
    int n = t >> 4;
    const uint4* hp = reinterpret_cast<const uint4*>(hin + (size_t)n * 16);
    uint4 ha = hp[0], hb = hp[1];
    float acc = agg[t] * invdeg[n] + bias[o];
    unsigned dw[8] = {ha.x, ha.y, ha.z, ha.w, hb.x, hb.y, hb.z, hb.w};
    #pragma unroll
    for (int j = 0; j < 8; ++j) {
        h2f p = u2h(dw[j]);
        acc += (float)p[0] * root[(2 * j) * 16 + o] + (float)p[1] * root[(2 * j + 1) * 16 + o];
    }
    hout[t] = __builtin_bit_cast(ushort, (_Float16)fmaxf(acc, 0.0f));
}

extern "C" void kernel_launch(void* const* d_in, const int* in_sizes, int n_in,
                              void* d_out, int out_size, void* d_ws, size_t ws_size,
                              hipStream_t stream) {
    const float* x      = (const float*)d_in[0];
    const int*   eidx   = (const int*)d_in[1];
    const float* eattr  = (const float*)d_in[2];
    const float* W1     = (const float*)d_in[3];
    const float* root1  = (const float*)d_in[4];
    const float* b1     = (const float*)d_in[5];
    const float* W2     = (const float*)d_in[6];
    const float* root2  = (const float*)d_in[7];
    const float* b2     = (const float*)d_in[8];
    const float* W3     = (const float*)d_in[9];
    const float* root3  = (const float*)d_in[10];
    const float* b3     = (const float*)d_in[11];
    const float* fcw    = (const float*)d_in[12];
    const float* fcb    = (const float*)d_in[13];
    float* out = (float*)d_out;

    const int N = in_sizes[0] / 2;
    const int E = in_sizes[2] / 2;
    const int* src = eidx;
    const int* dst = eidx + E;
    const int BT = 256;
    const int B = (N + BW - 1) / BW;

    // ---- workspace layout (bytes) ----
    char* w = (char*)d_ws;
    size_t off = 0;
    uint2* epack = (uint2*)(w + off); off += (size_t)E * 8;
    uint2* bin   = (uint2*)(w + off); off += (size_t)E * 8;
    int* bcnt    = (int*)(w + off);   off += 256 * 4;
    int* bbase   = (int*)(w + off);   off += 257 * 4;
    int* bcursor = (int*)(w + off);   off += 256 * 4;
    int* offs    = (int*)(w + off);   off += ((size_t)N + 1) * 4; off = (off + 15) & ~(size_t)15;
    ushort* hH1  = (ushort*)(w + off); off += (size_t)N * 32;
    ushort* hH2  = (ushort*)(w + off); off += (size_t)N * 32;
    size_t need_csr = off;

    if (ws_size >= need_csr && B <= 256 && N <= (1 << 17)) {
        // ---- binned CSR build ----
        hipMemsetAsync(bcnt, 0, 256 * 4, stream);
        bucket_hist_kernel<<<1024, BT, 0, stream>>>(dst, bcnt, E, B);
        bucket_scan_kernel<<<1, 256, 0, stream>>>(bcnt, bbase, bcursor, B, E);
        bin_kernel<<<(E + TILE - 1) / TILE, BT, 0, stream>>>(eattr, src, dst, bbase,
                                                             bcursor, bin, E);
        bucket_scatter_kernel<<<B, 256, 0, stream>>>(bin, bbase, epack, offs, N, E);

        // ---- fused layers ----
        int node_grid = (N * 16 + BT - 1) / BT;
        int pair_grid = (N * 8 + BT - 1) / BT;
        csr2_kernel<<<node_grid, BT, 0, stream>>>(x, epack, offs, W1, root1, b1, hH1, N);
        csr16c_kernel<0><<<pair_grid, BT, 0, stream>>>(hH1, epack, offs, W2, root2, b2,
                                                       hH2, nullptr, nullptr, nullptr, N);
        // layer 3 with fused FC + sigmoid -> out
        csr16c_kernel<1><<<pair_grid, BT, 0, stream>>>(hH2, epack, offs, W3, root3, b3,
                                                       nullptr, fcw, fcb, out, N);
    } else {
        // ---- fallback: atomic path ----
        float* agg = (float*)d_ws;                       // N*16
        float* deg = agg + (size_t)N * 16;               // N
        size_t f17 = ((size_t)N * 17 + 7) & ~(size_t)7;
        ushort* fH1 = (ushort*)((float*)d_ws + f17);
        ushort* fH2 = fH1 + (size_t)N * 16;
        const int EG = 2048;
        int node_grid = (N * 16 + BT - 1) / BT;

        hipMemsetAsync(deg, 0, (size_t)N * 4, stream);
        deg_count_kernel<<<2048, BT, 0, stream>>>(dst, deg, E);
        deg_inv_kernel<<<(N + BT - 1) / BT, BT, 0, stream>>>(deg, N);

        hipMemsetAsync(agg, 0, (size_t)N * 64, stream);
        edge2_fb<<<EG, BT, 0, stream>>>(x, dst, eattr, src, W1, agg, E);
        finalize2h_fb<<<node_grid, BT, 0, stream>>>(x, root1, b1, deg, agg, fH1, N);

        hipMemsetAsync(agg, 0, (size_t)N * 64, stream);
        edge16h_fb<<<EG, BT, 0, stream>>>(fH1, dst, eattr, src, W2, agg, E);
        finalize16h_fb<<<node_grid, BT, 0, stream>>>(fH1, root2, b2, deg, agg, fH2, N);

        hipMemsetAsync(agg, 0, (size_t)N * 64, stream);
        edge16h_fb<<<EG, BT, 0, stream>>>(fH2, dst, eattr, src, W3, agg, E);
        finalize16h_fb<<<node_grid, BT, 0, stream>>>(fH2, root3, b3, deg, agg, fH1, N);

        fc_kernel<<<(N + BT - 1) / BT, BT, 0, stream>>>(fH1, fcw, fcb, out, N);
    }
}

// Round 16
// 275.612 us; speedup vs baseline: 1.0411x; 1.0411x over previous
//
#include <hip/hip_runtime.h>
#include <math.h>

// ---------------------------------------------------------------------------
// SplineConv GNN, 3 layers, K=5, dim=2, mean aggr, root+bias, ReLU, FC+sigmoid.
//
// Round 16 = round 14 (best, 282.7us; csr16b 2-ch/thread, c*20 geometry,
// FC fused into layer 3) + ONE isolated change: csr2 also goes 2-ch/thread
// (csr2b, 8 threads/edge) -- csr2 is decode/record-bound (per-lane compute is
// 8 MACs), so amortizing record read + decode + x-row gather over 2 channels
// halves its dominant cost. R15's LDS-geometry change REVERTED (measured
// worse: 1.25e7 vs 8.1e6 conflict cycles; bank model not predictive).
// ---------------------------------------------------------------------------

#define KS 5
#define BW 512          // bucket width (nodes); B <= 256 for N <= 131072
#define TILE 4096       // edges per bin block

typedef _Float16 h2f __attribute__((ext_vector_type(2)));

__device__ __forceinline__ h2f u2h(unsigned u) { return __builtin_bit_cast(h2f, u); }

#if __has_builtin(__builtin_amdgcn_fdot2)
__device__ __forceinline__ float fdot2(h2f a, h2f b, float c) {
    return __builtin_amdgcn_fdot2(a, b, c, false);
}
#else
__device__ __forceinline__ float fdot2(h2f a, h2f b, float c) {
    return c + (float)a[0] * (float)b[0] + (float)a[1] * (float)b[1];
}
#endif

__device__ __forceinline__ unsigned packh2(float lo, float hi) {
    return (unsigned)__builtin_bit_cast(ushort, (_Float16)lo) |
           ((unsigned)__builtin_bit_cast(ushort, (_Float16)hi) << 16);
}

// ---- A0: bucket histogram ---------------------------------------------------
__global__ void bucket_hist_kernel(const int* __restrict__ dst, int* __restrict__ bcnt,
                                   int E, int B) {
    __shared__ int lh[256];
    lh[threadIdx.x] = 0;
    __syncthreads();
    int stride = gridDim.x * blockDim.x;
    for (int e = blockIdx.x * blockDim.x + threadIdx.x; e < E; e += stride)
        atomicAdd(&lh[dst[e] >> 9], 1);
    __syncthreads();
    int c = lh[threadIdx.x];
    if ((int)threadIdx.x < B && c) atomicAdd(&bcnt[threadIdx.x], c);
}

// ---- A1: bucket scan (1 block) + cursor init --------------------------------
__global__ void bucket_scan_kernel(const int* __restrict__ bcnt, int* __restrict__ bbase,
                                   int* __restrict__ bcursor, int B, int E) {
    __shared__ int sh[256];
    int v = ((int)threadIdx.x < B) ? bcnt[threadIdx.x] : 0;
    sh[threadIdx.x] = v;
    __syncthreads();
    for (int off = 1; off < 256; off <<= 1) {
        int t = (threadIdx.x >= (unsigned)off) ? sh[threadIdx.x - off] : 0;
        __syncthreads();
        sh[threadIdx.x] += t;
        __syncthreads();
    }
    if ((int)threadIdx.x < B) {
        bbase[threadIdx.x] = sh[threadIdx.x] - v;   // exclusive
        bcursor[threadIdx.x] = 0;
    }
    if (threadIdx.x == 0) bbase[B] = E;
}

// ---- A2: tile-radix bin -----------------------------------------------------
// bin rec = { src | dloc_lo8<<17 | w00<<25 | dloc_hi1<<30 , f16(f0)|f16(f1)<<16 }
__global__ __launch_bounds__(256) void bin_kernel(
        const float* __restrict__ eattr, const int* __restrict__ src,
        const int* __restrict__ dst, const int* __restrict__ bbase,
        int* __restrict__ bcursor, uint2* __restrict__ bin, int E) {
    __shared__ int lh[256];
    __shared__ int labs[256];
    __shared__ int lcur[256];
    lh[threadIdx.x] = 0;
    lcur[threadIdx.x] = 0;
    __syncthreads();
    int t0 = blockIdx.x * TILE;
    #pragma unroll
    for (int it = 0; it < TILE / 256; ++it) {
        int e = t0 + it * 256 + threadIdx.x;
        if (e < E) atomicAdd(&lh[dst[e] >> 9], 1);
    }
    __syncthreads();
    {
        int c = lh[threadIdx.x];
        if (c) labs[threadIdx.x] = bbase[threadIdx.x] + atomicAdd(&bcursor[threadIdx.x], c);
    }
    __syncthreads();
    #pragma unroll
    for (int it = 0; it < TILE / 256; ++it) {
        int e = t0 + it * 256 + threadIdx.x;
        if (e < E) {
            float2 ea = reinterpret_cast<const float2*>(eattr)[e];
            float a0 = ea.x * (float)(KS - 1);
            float a1 = ea.y * (float)(KS - 1);
            float k0 = fminf(fmaxf(floorf(a0), 0.0f), (float)(KS - 2));
            float k1 = fminf(fmaxf(floorf(a1), 0.0f), (float)(KS - 2));
            float f0 = a0 - k0, f1 = a1 - k1;
            unsigned w00 = (unsigned)((int)k0 + KS * (int)k1);
            int d = dst[e];
            int b = d >> 9;
            unsigned dloc = (unsigned)(d & 511);
            unsigned w0 = (unsigned)src[e] | ((dloc & 255u) << 17) | (w00 << 25) |
                          ((dloc >> 8) << 30);
            int p = atomicAdd(&lcur[b], 1);
            bin[labs[b] + p] = make_uint2(w0, packh2(f0, f1));
        }
    }
}

// ---- A3: within-bucket scatter to CSR + offs emission ----------------------
__global__ __launch_bounds__(256) void bucket_scatter_kernel(
        const uint2* __restrict__ bin, const int* __restrict__ bbase,
        uint2* __restrict__ epack, int* __restrict__ offs, int N, int E) {
    __shared__ int lcnt[512];
    __shared__ int loff[512];
    __shared__ int lcur[512];
    __shared__ int ssc[256];
    int tid = threadIdx.x;
    int b = blockIdx.x;
    int base = bbase[b];
    int cntb = bbase[b + 1] - base;
    int nbase = b << 9;
    lcnt[tid] = 0; lcnt[tid + 256] = 0;
    lcur[tid] = 0; lcur[tid + 256] = 0;
    __syncthreads();
    for (int r = tid; r < cntb; r += 256) {
        unsigned w0 = bin[base + r].x;
        int dloc = (int)(((w0 >> 17) & 255u) | (((w0 >> 30) & 1u) << 8));
        atomicAdd(&lcnt[dloc], 1);
    }
    __syncthreads();
    int a0 = lcnt[2 * tid], a1 = lcnt[2 * tid + 1];
    ssc[tid] = a0 + a1;
    __syncthreads();
    for (int off = 1; off < 256; off <<= 1) {
        int t = (tid >= off) ? ssc[tid - off] : 0;
        __syncthreads();
        ssc[tid] += t;
        __syncthreads();
    }
    int ex = (tid > 0) ? ssc[tid - 1] : 0;
    loff[2 * tid] = ex;
    loff[2 * tid + 1] = ex + a0;
    __syncthreads();
    for (int i = tid; i < 512; i += 256) {
        int n = nbase + i;
        if (n < N) offs[n] = base + loff[i];
    }
    if (b == 0 && tid == 0) offs[N] = E;
    for (int r = tid; r < cntb; r += 256) {
        uint2 rec = bin[base + r];
        int dloc = (int)(((rec.x >> 17) & 255u) | (((rec.x >> 30) & 1u) << 8));
        int p = atomicAdd(&lcur[dloc], 1);
        epack[base + loff[dloc] + p] = make_uint2(rec.x & 0x3E01FFFFu, rec.y);
    }
}

__device__ __forceinline__ void decode8(uint2 pk, int& s, float b[4], int wi[4]) {
    s = (int)(pk.x & 0x1FFFFFFu);
    int w00 = (int)((pk.x >> 25) & 31u);
    wi[0] = w00; wi[1] = w00 + 1; wi[2] = w00 + KS; wi[3] = w00 + KS + 1;
    h2f f = u2h(pk.y);
    float f0 = (float)f[0], f1 = (float)f[1];
    float g0 = 1.0f - f0, g1 = 1.0f - f1;
    b[0] = g0 * g1; b[1] = f0 * g1; b[2] = g0 * f1; b[3] = f0 * f1;
}

// ---- fused layer 1, 2 channels/thread (8 threads/edge) ---------------------
// Thread c (= t&7) handles channels c and c+8. LDS layout unchanged
// ([k*32 + o*2 + i] floats); lane reads float2 at o=c and o=c+8 (+16 dwords).
__global__ __launch_bounds__(256, 8) void csr2b_kernel(
        const float* __restrict__ x,
        const uint2* __restrict__ epack,
        const int* __restrict__ offs,
        const float* __restrict__ W,      // [25,2,16]
        const float* __restrict__ root,   // [2,16]
        const float* __restrict__ bias,   // [16]
        ushort* __restrict__ hout,        // [N,16] f16
        int N) {
    __shared__ float Wl[25 * 32];
    for (int idx = threadIdx.x; idx < 25 * 32; idx += blockDim.x) {
        int k = idx >> 5;
        int r = idx & 31;
        int i = r >> 4;
        int o = r & 15;
        Wl[k * 32 + o * 2 + i] = W[idx];
    }
    __syncthreads();

    int t = blockIdx.x * blockDim.x + threadIdx.x;
    if (t >= N * 8) return;
    int c = t & 7;
    int n = t >> 3;
    int row = offs[n], end = offs[n + 1];
    int s0 = c * 2, s1 = s0 + 16;

    float acc0 = 0.0f, acc1 = 0.0f;
    uint2 pk = epack[(row < end) ? row : 0];
    for (int j = row; j < end; ++j) {
        uint2 cur = pk;
        int jn = j + 1;
        pk = epack[(jn < end) ? jn : j];
        int s;
        float b[4];
        int wi[4];
        decode8(cur, s, b, wi);
        float2 xv = reinterpret_cast<const float2*>(x)[s];
        #pragma unroll
        for (int sp = 0; sp < 4; ++sp) {
            const float* wbase = &Wl[wi[sp] * 32];
            float2 w0 = *reinterpret_cast<const float2*>(wbase + s0);
            float2 w1 = *reinterpret_cast<const float2*>(wbase + s1);
            acc0 += b[sp] * (xv.x * w0.x + xv.y * w0.y);
            acc1 += b[sp] * (xv.x * w1.x + xv.y * w1.y);
        }
    }
    float inv = 1.0f / fmaxf((float)(end - row), 1.0f);
    float2 xn = reinterpret_cast<const float2*>(x)[n];
    float r0 = acc0 * inv + xn.x * root[c] + xn.y * root[16 + c] + bias[c];
    float r1 = acc1 * inv + xn.x * root[c + 8] + xn.y * root[24 + c] + bias[c + 8];
    hout[(size_t)n * 16 + c] = __builtin_bit_cast(ushort, (_Float16)fmaxf(r0, 0.0f));
    hout[(size_t)n * 16 + c + 8] = __builtin_bit_cast(ushort, (_Float16)fmaxf(r1, 0.0f));
}

// ---- fused layers 2/3: 2 channels/thread (8 threads/edge) — R14 exact ------
// LDS: pair-row (k, c) at dword k*160 + c*20, 16 dwords used:
//   dwords 0-7  = channel 2c   (f16 pairs over i: dword d holds i=2d,2d+1)
//   dwords 8-15 = channel 2c+1
// Root at dword 4000 + c*20. Total 16.64KB -> 8 blocks/CU.
// FUSE_FC=1: 8-lane shfl reduce with fcw, lane c==0 writes sigmoid out[n].
template <int FUSE_FC>
__global__ __launch_bounds__(256, 8) void csr16b_kernel(
        const ushort* __restrict__ hh,
        const uint2* __restrict__ epack,
        const int* __restrict__ offs,
        const float* __restrict__ W,      // [25,16,16] f32
        const float* __restrict__ root,   // [16,16] f32
        const float* __restrict__ bias,   // [16]
        ushort* __restrict__ hout,        // [N,16] f16 (FUSE_FC=0)
        const float* __restrict__ fcw,    // [16]       (FUSE_FC=1)
        const float* __restrict__ fcb,    // [1]        (FUSE_FC=1)
        float* __restrict__ out,          // [N]        (FUSE_FC=1)
        int N) {
    __shared__ unsigned Wl[25 * 160 + 160];
    for (int idx = threadIdx.x; idx < 25 * 128 + 128; idx += blockDim.x) {
        if (idx < 25 * 128) {
            int k = idx >> 7;
            int d = idx & 127;
            int c = d >> 4;
            int dd = d & 15;
            int ch = 2 * c + (dd >> 3);
            int i0 = (dd & 7) * 2;
            Wl[k * 160 + c * 20 + dd] =
                packh2(W[k * 256 + i0 * 16 + ch], W[k * 256 + (i0 + 1) * 16 + ch]);
        } else {
            int d = idx - 25 * 128;
            int c = d >> 4;
            int dd = d & 15;
            int ch = 2 * c + (dd >> 3);
            int i0 = (dd & 7) * 2;
            Wl[4000 + c * 20 + dd] =
                packh2(root[i0 * 16 + ch], root[(i0 + 1) * 16 + ch]);
        }
    }
    __syncthreads();

    int t = blockIdx.x * blockDim.x + threadIdx.x;
    if (t >= N * 8) return;
    int c = t & 7;
    int n = t >> 3;
    int row = offs[n], end = offs[n + 1];
    int s0 = c * 20;

    float acc0 = 0.0f, acc1 = 0.0f;
    uint2 pk = epack[(row < end) ? row : 0];
    for (int j = row; j < end; ++j) {
        uint2 cur = pk;
        int jn = j + 1;
        pk = epack[(jn < end) ? jn : j];
        int s;
        float b[4];
        int wi[4];
        decode8(cur, s, b, wi);
        const uint4* hp = reinterpret_cast<const uint4*>(hh + (size_t)s * 16);
        uint4 ha = hp[0], hb = hp[1];
        #pragma unroll
        for (int sp = 0; sp < 4; ++sp) {
            int kb = wi[sp] * 160 + s0;
            uint4 wa = *reinterpret_cast<const uint4*>(&Wl[kb]);
            uint4 wb = *reinterpret_cast<const uint4*>(&Wl[kb + 4]);
            uint4 wc = *reinterpret_cast<const uint4*>(&Wl[kb + 8]);
            uint4 wd = *reinterpret_cast<const uint4*>(&Wl[kb + 12]);
            float p0 = 0.0f, p1 = 0.0f;
            p0 = fdot2(u2h(ha.x), u2h(wa.x), p0);
            p0 = fdot2(u2h(ha.y), u2h(wa.y), p0);
            p0 = fdot2(u2h(ha.z), u2h(wa.z), p0);
            p0 = fdot2(u2h(ha.w), u2h(wa.w), p0);
            p0 = fdot2(u2h(hb.x), u2h(wb.x), p0);
            p0 = fdot2(u2h(hb.y), u2h(wb.y), p0);
            p0 = fdot2(u2h(hb.z), u2h(wb.z), p0);
            p0 = fdot2(u2h(hb.w), u2h(wb.w), p0);
            p1 = fdot2(u2h(ha.x), u2h(wc.x), p1);
            p1 = fdot2(u2h(ha.y), u2h(wc.y), p1);
            p1 = fdot2(u2h(ha.z), u2h(wc.z), p1);
            p1 = fdot2(u2h(ha.w), u2h(wc.w), p1);
            p1 = fdot2(u2h(hb.x), u2h(wd.x), p1);
            p1 = fdot2(u2h(hb.y), u2h(wd.y), p1);
            p1 = fdot2(u2h(hb.z), u2h(wd.z), p1);
            p1 = fdot2(u2h(hb.w), u2h(wd.w), p1);
            acc0 = fmaf(b[sp], p0, acc0);
            acc1 = fmaf(b[sp], p1, acc1);
        }
    }
    float inv = 1.0f / fmaxf((float)(end - row), 1.0f);
    acc0 *= inv;
    acc1 *= inv;
    {
        const uint4* hp = reinterpret_cast<const uint4*>(hh + (size_t)n * 16);
        uint4 ha = hp[0], hb = hp[1];
        uint4 ra = *reinterpret_cast<const uint4*>(&Wl[4000 + s0]);
        uint4 rb = *reinterpret_cast<const uint4*>(&Wl[4000 + s0 + 4]);
        uint4 rc = *reinterpret_cast<const uint4*>(&Wl[4000 + s0 + 8]);
        uint4 rd = *reinterpret_cast<const uint4*>(&Wl[4000 + s0 + 12]);
        float p0 = 0.0f, p1 = 0.0f;
        p0 = fdot2(u2h(ha.x), u2h(ra.x), p0);
        p0 = fdot2(u2h(ha.y), u2h(ra.y), p0);
        p0 = fdot2(u2h(ha.z), u2h(ra.z), p0);
        p0 = fdot2(u2h(ha.w), u2h(ra.w), p0);
        p0 = fdot2(u2h(hb.x), u2h(rb.x), p0);
        p0 = fdot2(u2h(hb.y), u2h(rb.y), p0);
        p0 = fdot2(u2h(hb.z), u2h(rb.z), p0);
        p0 = fdot2(u2h(hb.w), u2h(rb.w), p0);
        p1 = fdot2(u2h(ha.x), u2h(rc.x), p1);
        p1 = fdot2(u2h(ha.y), u2h(rc.y), p1);
        p1 = fdot2(u2h(ha.z), u2h(rc.z), p1);
        p1 = fdot2(u2h(ha.w), u2h(rc.w), p1);
        p1 = fdot2(u2h(hb.x), u2h(rd.x), p1);
        p1 = fdot2(u2h(hb.y), u2h(rd.y), p1);
        p1 = fdot2(u2h(hb.z), u2h(rd.z), p1);
        p1 = fdot2(u2h(hb.w), u2h(rd.w), p1);
        acc0 += p0 + bias[2 * c];
        acc1 += p1 + bias[2 * c + 1];
    }
    float h0 = fmaxf(acc0, 0.0f);
    float h1 = fmaxf(acc1, 0.0f);
    if (FUSE_FC == 0) {
        reinterpret_cast<unsigned*>(hout)[(size_t)n * 8 + c] = packh2(h0, h1);
    } else {
        float partial = h0 * fcw[2 * c] + h1 * fcw[2 * c + 1];
        partial += __shfl_xor(partial, 1, 8);
        partial += __shfl_xor(partial, 2, 8);
        partial += __shfl_xor(partial, 4, 8);
        if (c == 0) out[n] = 1.0f / (1.0f + expf(-(partial + fcb[0])));
    }
}

// ---- final FC + sigmoid (fallback paths only) ------------------------------
__global__ void fc_kernel(const ushort* __restrict__ h,
                          const float* __restrict__ fcw,
                          const float* __restrict__ fcb,
                          float* __restrict__ out, int N) {
    int n = blockIdx.x * blockDim.x + threadIdx.x;
    if (n >= N) return;
    const uint4* hp = reinterpret_cast<const uint4*>(h + (size_t)n * 16);
    uint4 ha = hp[0], hb = hp[1];
    unsigned dw[8] = {ha.x, ha.y, ha.z, ha.w, hb.x, hb.y, hb.z, hb.w};
    float acc = fcb[0];
    #pragma unroll
    for (int j = 0; j < 8; ++j) {
        h2f p = u2h(dw[j]);
        acc += (float)p[0] * fcw[2 * j] + (float)p[1] * fcw[2 * j + 1];
    }
    out[n] = 1.0f / (1.0f + expf(-acc));
}

// ---------------------------------------------------------------------------
// Fallback path (ws too small or N too large): atomic kernels.
// ---------------------------------------------------------------------------
__global__ void deg_count_kernel(const int* __restrict__ dst, float* __restrict__ deg, int E) {
    int stride = gridDim.x * blockDim.x;
    for (int e = blockIdx.x * blockDim.x + threadIdx.x; e < E; e += stride)
        atomicAdd(&deg[dst[e]], 1.0f);
}
__global__ void deg_inv_kernel(float* __restrict__ deg, int N) {
    int i = blockIdx.x * blockDim.x + threadIdx.x;
    if (i < N) deg[i] = 1.0f / fmaxf(deg[i], 1.0f);
}
__device__ __forceinline__ void compute_basis(const float* eattr, const int* srcp, int e,
                                              int& s, float b[4], int wi[4]) {
    float2 ea = reinterpret_cast<const float2*>(eattr)[e];
    float a0 = ea.x * (float)(KS - 1);
    float a1 = ea.y * (float)(KS - 1);
    float k0 = fminf(fmaxf(floorf(a0), 0.0f), (float)(KS - 2));
    float k1 = fminf(fmaxf(floorf(a1), 0.0f), (float)(KS - 2));
    float f0 = a0 - k0, f1 = a1 - k1;
    int i0 = (int)k0, i1 = (int)k1;
    int w00 = i0 + KS * i1;
    wi[0] = w00; wi[1] = w00 + 1; wi[2] = w00 + KS; wi[3] = w00 + KS + 1;
    float g0 = 1.0f - f0, g1 = 1.0f - f1;
    b[0] = g0 * g1; b[1] = f0 * g1; b[2] = g0 * f1; b[3] = f0 * f1;
    s = srcp[e];
}
__global__ __launch_bounds__(256) void edge16h_fb(
        const ushort* __restrict__ hh, const int* __restrict__ dst,
        const float* __restrict__ eattr, const int* __restrict__ srcp,
        const float* __restrict__ W, float* __restrict__ agg, int E) {
    __shared__ unsigned Wl[25 * 192];
    for (int idx = threadIdx.x; idx < 25 * 128; idx += blockDim.x) {
        int k = idx >> 7;
        int d = idx & 127;
        int o = d >> 3;
        int j = d & 7;
        int i0 = ((j >> 2) << 3) + ((j & 3) << 1);
        Wl[k * 192 + o * 12 + j] =
            packh2(W[k * 256 + i0 * 16 + o], W[k * 256 + (i0 + 1) * 16 + o]);
    }
    __syncthreads();
    int gs = gridDim.x * blockDim.x;
    int total = E * 16;
    for (int t = blockIdx.x * blockDim.x + threadIdx.x; t < total; t += gs) {
        int e = t >> 4;
        int o = t & 15;
        int s;
        float b[4];
        int wi[4];
        compute_basis(eattr, srcp, e, s, b, wi);
        const uint4* hp = reinterpret_cast<const uint4*>(hh + (size_t)s * 16);
        uint4 ha = hp[0], hb = hp[1];
        float acc = 0.0f;
        #pragma unroll
        for (int sp = 0; sp < 4; ++sp) {
            int kb = wi[sp] * 192 + o * 12;
            uint4 wa = *reinterpret_cast<const uint4*>(&Wl[kb]);
            uint4 wb = *reinterpret_cast<const uint4*>(&Wl[kb + 4]);
            float p = 0.0f;
            p = fdot2(u2h(ha.x), u2h(wa.x), p);
            p = fdot2(u2h(ha.y), u2h(wa.y), p);
            p = fdot2(u2h(ha.z), u2h(wa.z), p);
            p = fdot2(u2h(ha.w), u2h(wa.w), p);
            p = fdot2(u2h(hb.x), u2h(wb.x), p);
            p = fdot2(u2h(hb.y), u2h(wb.y), p);
            p = fdot2(u2h(hb.z), u2h(wb.z), p);
            p = fdot2(u2h(hb.w), u2h(wb.w), p);
            acc = fmaf(b[sp], p, acc);
        }
        atomicAdd(&agg[(size_t)dst[e] * 16 + o], acc);
    }
}
__global__ __launch_bounds__(256) void edge2_fb(
        const float* __restrict__ x, const int* __restrict__ dst,
        const float* __restrict__ eattr, const int* __restrict__ srcp,
        const float* __restrict__ W, float* __restrict__ agg, int E) {
    __shared__ float Wl[25 * 32];
    for (int idx = threadIdx.x; idx < 25 * 32; idx += blockDim.x) {
        int k = idx >> 5;
        int r = idx & 31;
        int i = r >> 4;
        int o = r & 15;
        Wl[k * 32 + o * 2 + i] = W[idx];
    }
    __syncthreads();
    int gs = gridDim.x * blockDim.x;
    int total = E * 16;
    for (int t = blockIdx.x * blockDim.x + threadIdx.x; t < total; t += gs) {
        int e = t >> 4;
        int o = t & 15;
        int s;
        float b[4];
        int wi[4];
        compute_basis(eattr, srcp, e, s, b, wi);
        float2 xv = reinterpret_cast<const float2*>(x)[s];
        float acc = 0.0f;
        #pragma unroll
        for (int sp = 0; sp < 4; ++sp) {
            float2 w = *reinterpret_cast<const float2*>(&Wl[wi[sp] * 32 + o * 2]);
            acc += b[sp] * (xv.x * w.x + xv.y * w.y);
        }
        atomicAdd(&agg[(size_t)dst[e] * 16 + o], acc);
    }
}
__global__ void finalize2h_fb(const float* __restrict__ x, const float* __restrict__ root,
                              const float* __restrict__ bias, const float* __restrict__ invdeg,
                              const float* __restrict__ agg, ushort* __restrict__ hout, int N) {
    int t = blockIdx.x * blockDim.x + threadIdx.x;
    if (t >= N * 16) return;
    int o = t & 15;
    int n = t >> 4;
    float2 xv = reinterpret_cast<const float2*>(x)[n];
    float acc = agg[t] * invdeg[n] + xv.x * root[o] + xv.y * root[16 + o] + bias[o];
    hout[t] = __builtin_bit_cast(ushort, (_Float16)fmaxf(acc, 0.0f));
}
__global__ void finalize16h_fb(const ushort* __restrict__ hin, const float* __restrict__ root,
                               const float* __restrict__ bias, const float* __restrict__ invdeg,
                               const float* __restrict__ agg, ushort* __restrict__ hout, int N) {
    int t = blockIdx.x * blockDim.x + threadIdx.x;
    if (t >= N * 16) return;
    int o = t & 15;
    int n = t >> 4;
    const uint4* hp = reinterpret_cast<const uint4*>(hin + (size_t)n * 16);
    uint4 ha = hp[0], hb = hp[1];
    float acc = agg[t] * invdeg[n] + bias[o];
    unsigned dw[8] = {ha.x, ha.y, ha.z, ha.w, hb.x, hb.y, hb.z, hb.w};
    #pragma unroll
    for (int j = 0; j < 8; ++j) {
        h2f p = u2h(dw[j]);
        acc += (float)p[0] * root[(2 * j) * 16 + o] + (float)p[1] * root[(2 * j + 1) * 16 + o];
    }
    hout[t] = __builtin_bit_cast(ushort, (_Float16)fmaxf(acc, 0.0f));
}

extern "C" void kernel_launch(void* const* d_in, const int* in_sizes, int n_in,
                              void* d_out, int out_size, void* d_ws, size_t ws_size,
                              hipStream_t stream) {
    const float* x      = (const float*)d_in[0];
    const int*   eidx   = (const int*)d_in[1];
    const float* eattr  = (const float*)d_in[2];
    const float* W1     = (const float*)d_in[3];
    const float* root1  = (const float*)d_in[4];
    const float* b1     = (const float*)d_in[5];
    const float* W2     = (const float*)d_in[6];
    const float* root2  = (const float*)d_in[7];
    const float* b2     = (const float*)d_in[8];
    const float* W3     = (const float*)d_in[9];
    const float* root3  = (const float*)d_in[10];
    const float* b3     = (const float*)d_in[11];
    const float* fcw    = (const float*)d_in[12];
    const float* fcb    = (const float*)d_in[13];
    float* out = (float*)d_out;

    const int N = in_sizes[0] / 2;
    const int E = in_sizes[2] / 2;
    const int* src = eidx;
    const int* dst = eidx + E;
    const int BT = 256;
    const int B = (N + BW - 1) / BW;

    // ---- workspace layout (bytes) ----
    char* w = (char*)d_ws;
    size_t off = 0;
    uint2* epack = (uint2*)(w + off); off += (size_t)E * 8;
    uint2* bin   = (uint2*)(w + off); off += (size_t)E * 8;
    int* bcnt    = (int*)(w + off);   off += 256 * 4;
    int* bbase   = (int*)(w + off);   off += 257 * 4;
    int* bcursor = (int*)(w + off);   off += 256 * 4;
    int* offs    = (int*)(w + off);   off += ((size_t)N + 1) * 4; off = (off + 15) & ~(size_t)15;
    ushort* hH1  = (ushort*)(w + off); off += (size_t)N * 32;
    ushort* hH2  = (ushort*)(w + off); off += (size_t)N * 32;
    size_t need_csr = off;

    if (ws_size >= need_csr && B <= 256 && N <= (1 << 17)) {
        // ---- binned CSR build ----
        hipMemsetAsync(bcnt, 0, 256 * 4, stream);
        bucket_hist_kernel<<<1024, BT, 0, stream>>>(dst, bcnt, E, B);
        bucket_scan_kernel<<<1, 256, 0, stream>>>(bcnt, bbase, bcursor, B, E);
        bin_kernel<<<(E + TILE - 1) / TILE, BT, 0, stream>>>(eattr, src, dst, bbase,
                                                             bcursor, bin, E);
        bucket_scatter_kernel<<<B, 256, 0, stream>>>(bin, bbase, epack, offs, N, E);

        // ---- fused layers ----
        int pair_grid = (N * 8 + BT - 1) / BT;
        csr2b_kernel<<<pair_grid, BT, 0, stream>>>(x, epack, offs, W1, root1, b1, hH1, N);
        csr16b_kernel<0><<<pair_grid, BT, 0, stream>>>(hH1, epack, offs, W2, root2, b2,
                                                       hH2, nullptr, nullptr, nullptr, N);
        // layer 3 with fused FC + sigmoid -> out
        csr16b_kernel<1><<<pair_grid, BT, 0, stream>>>(hH2, epack, offs, W3, root3, b3,
                                                       nullptr, fcw, fcb, out, N);
    } else {
        // ---- fallback: atomic path ----
        float* agg = (float*)d_ws;                       // N*16
        float* deg = agg + (size_t)N * 16;               // N
        size_t f17 = ((size_t)N * 17 + 7) & ~(size_t)7;
        ushort* fH1 = (ushort*)((float*)d_ws + f17);
        ushort* fH2 = fH1 + (size_t)N * 16;
        const int EG = 2048;
        int node_grid = (N * 16 + BT - 1) / BT;

        hipMemsetAsync(deg, 0, (size_t)N * 4, stream);
        deg_count_kernel<<<2048, BT, 0, stream>>>(dst, deg, E);
        deg_inv_kernel<<<(N + BT - 1) / BT, BT, 0, stream>>>(deg, N);

        hipMemsetAsync(agg, 0, (size_t)N * 64, stream);
        edge2_fb<<<EG, BT, 0, stream>>>(x, dst, eattr, src, W1, agg, E);
        finalize2h_fb<<<node_grid, BT, 0, stream>>>(x, root1, b1, deg, agg, fH1, N);

        hipMemsetAsync(agg, 0, (size_t)N * 64, stream);
        edge16h_fb<<<EG, BT, 0, stream>>>(fH1, dst, eattr, src, W2, agg, E);
        finalize16h_fb<<<node_grid, BT, 0, stream>>>(fH1, root2, b2, deg, agg, fH2, N);

        hipMemsetAsync(agg, 0, (size_t)N * 64, stream);
        edge16h_fb<<<EG, BT, 0, stream>>>(fH2, dst, eattr, src, W3, agg, E);
        finalize16h_fb<<<node_grid, BT, 0, stream>>>(fH2, root3, b3, deg, agg, fH1, N);

        fc_kernel<<<(N + BT - 1) / BT, BT, 0, stream>>>(fH1, fcw, fcb, out, N);
    }
}